// Round 1
// baseline (344.190 us; speedup 1.0000x reference)
//
#include <hip/hip_runtime.h>
#include <math.h>

namespace {

constexpr int S = 256, B = 32, D = 512, H = 512;
constexpr int BH = B * H;          // 16384
constexpr int M1 = S * B;          // 8192  (rows of x viewed as (S*B, D))
constexpr int LDP = 68;            // padded LDS row stride in floats (272B, 16B-aligned)

// ---------------------------------------------------------------------------
// Kernel A: input projections.  pre[m][h] = sum_d x[m][d] * wm[h][d]
// x is (S,B,D) row-major == (M1, D) row-major with m = s*B+b.
// Dual-output (wm_z and wm_f share the x tile). 64x64 tile, BK=32, 256 thr,
// 4x4 register tile per thread per output.
// ---------------------------------------------------------------------------
__global__ __launch_bounds__(256) void proj_gemm(
    const float* __restrict__ x, const float* __restrict__ wmz,
    const float* __restrict__ wmf, float* __restrict__ pz,
    float* __restrict__ pf) {
  __shared__ float As[32][LDP];    // [k][m]
  __shared__ float Bzs[32][LDP];   // [k][n]
  __shared__ float Bfs[32][LDP];
  const int m0 = blockIdx.x * 64;
  const int n0 = blockIdx.y * 64;
  const int tid = threadIdx.x;
  const int tm = (tid & 15) * 4;
  const int tn = (tid >> 4) * 4;
  const int lr = tid >> 3;        // 0..31 (row within 64-row tile; +32 second pass)
  const int lk = (tid & 7) * 4;   // k offset 0..28
  float accz[4][4] = {};
  float accf[4][4] = {};
  for (int k0 = 0; k0 < D; k0 += 32) {
    #pragma unroll
    for (int rr = lr; rr < 64; rr += 32) {
      float4 av = *(const float4*)&x[(size_t)(m0 + rr) * D + k0 + lk];
      As[lk + 0][rr] = av.x; As[lk + 1][rr] = av.y;
      As[lk + 2][rr] = av.z; As[lk + 3][rr] = av.w;
      float4 bz = *(const float4*)&wmz[(size_t)(n0 + rr) * D + k0 + lk];
      Bzs[lk + 0][rr] = bz.x; Bzs[lk + 1][rr] = bz.y;
      Bzs[lk + 2][rr] = bz.z; Bzs[lk + 3][rr] = bz.w;
      float4 bf = *(const float4*)&wmf[(size_t)(n0 + rr) * D + k0 + lk];
      Bfs[lk + 0][rr] = bf.x; Bfs[lk + 1][rr] = bf.y;
      Bfs[lk + 2][rr] = bf.z; Bfs[lk + 3][rr] = bf.w;
    }
    __syncthreads();
    #pragma unroll
    for (int k = 0; k < 32; ++k) {
      float4 a4 = *(const float4*)&As[k][tm];
      float4 bz4 = *(const float4*)&Bzs[k][tn];
      float4 bf4 = *(const float4*)&Bfs[k][tn];
      float a[4] = {a4.x, a4.y, a4.z, a4.w};
      float vz[4] = {bz4.x, bz4.y, bz4.z, bz4.w};
      float vf[4] = {bf4.x, bf4.y, bf4.z, bf4.w};
      #pragma unroll
      for (int i = 0; i < 4; ++i) {
        #pragma unroll
        for (int j = 0; j < 4; ++j) {
          accz[i][j] = fmaf(a[i], vz[j], accz[i][j]);
          accf[i][j] = fmaf(a[i], vf[j], accf[i][j]);
        }
      }
    }
    __syncthreads();
  }
  #pragma unroll
  for (int i = 0; i < 4; ++i) {
    size_t row = (size_t)(m0 + tm + i) * H + n0 + tn;
    *(float4*)&pz[row] =
        make_float4(accz[i][0], accz[i][1], accz[i][2], accz[i][3]);
    *(float4*)&pf[row] =
        make_float4(accf[i][0], accf[i][1], accf[i][2], accf[i][3]);
  }
}

// ---------------------------------------------------------------------------
// Kernel B: sequential scan. One thread per (b,h).
// Forward: consumes pre_z/pre_f (in ws0/ws1), emits cells, scalar sensitivity
//          recurrences, and stores zf/fz/common (zf->ws0, fz->ws1, common->ws2).
// Backward: folds suffix products of `common` in-place: ws0 <- zf_t * P_t,
//           ws1 <- fz_t * P_t, and writes P0 (product of all common).
// ---------------------------------------------------------------------------
__global__ __launch_bounds__(256) void scan_kernel(
    const float* __restrict__ hidden_prev, const float* __restrict__ wz0,
    const float* __restrict__ wf0, const float* __restrict__ bz0,
    const float* __restrict__ bf0, const float* __restrict__ wvz_,
    const float* __restrict__ wvf_, const float* __restrict__ bsz_,
    const float* __restrict__ bsf_, float* __restrict__ ws0,
    float* __restrict__ ws1, float* __restrict__ ws2,
    float* __restrict__ P0_out, float* __restrict__ out_cells,
    float* __restrict__ out_newcell, float* __restrict__ out_wzn,
    float* __restrict__ out_wfn, float* __restrict__ out_bzn,
    float* __restrict__ out_bfn) {
  const int bh = blockIdx.x * 256 + threadIdx.x;
  const int h = bh & (H - 1);
  float cell = hidden_prev[bh];
  float wz = wz0[bh], wf = wf0[bh], bz = bz0[bh], bf = bf0[bh];
  const float wvz = wvz_[h], wvf = wvf_[h], bsz = bsz_[h], bsf = bsf_[h];
  for (int t = 0; t < S; ++t) {
    const size_t idx = (size_t)t * BH + bh;
    const float pz = ws0[idx];
    const float pf = ws1[idx];
    const float z = tanhf(fmaf(wvz, cell, pz) + bsz);
    const float f = 1.0f / (1.0f + expf(-(fmaf(wvf, cell, pf) + bsf)));
    const float zf = (1.0f - f) * (1.0f - z * z);
    const float fz = (cell - z) * (1.0f - f) * f;
    const float common = f + zf * wvz + fz * wvf;
    wz = fmaf(common, wz, cell * zf);
    wf = fmaf(common, wf, cell * fz);
    bz = fmaf(common, bz, zf);
    bf = fmaf(common, bf, fz);
    cell = cell * f + (1.0f - f) * z;
    out_cells[idx] = cell;
    ws0[idx] = zf;
    ws1[idx] = fz;
    ws2[idx] = common;
  }
  out_newcell[bh] = cell;
  out_wzn[bh] = wz;
  out_wfn[bh] = wf;
  out_bzn[bh] = bz;
  out_bfn[bh] = bf;
  float P = 1.0f;
  for (int t = S - 1; t >= 0; --t) {
    const size_t idx = (size_t)t * BH + bh;
    ws0[idx] *= P;
    ws1[idx] *= P;
    P *= ws2[idx];
  }
  P0_out[bh] = P;
}

// ---------------------------------------------------------------------------
// Kernel C: final sensitivity states.
//   Zn[b][h][d] = P0[b,h]*Z0[b][h][d] + sum_t Az[t][b][h] * x[t][b][d]
// (same for Fn with Af).  Batched GEMM, K = S = 256, operands K-major so
// tiles stage without transpose. Dual-output (shares the x tile).
// ---------------------------------------------------------------------------
__global__ __launch_bounds__(256) void out_gemm(
    const float* __restrict__ x, const float* __restrict__ Az,
    const float* __restrict__ Af, const float* __restrict__ P0,
    const float* __restrict__ Z0, const float* __restrict__ F0,
    float* __restrict__ Zn, float* __restrict__ Fn) {
  __shared__ float As[32][LDP];    // Az tile  [t][h]
  __shared__ float Afs[32][LDP];   // Af tile  [t][h]
  __shared__ float Xs[32][LDP];    // x tile   [t][d]
  const int d0 = blockIdx.x * 64;
  const int h0 = blockIdx.y * 64;
  const int b = blockIdx.z;
  const int tid = threadIdx.x;
  const int tm = (tid & 15) * 4;   // h within tile
  const int tn = (tid >> 4) * 4;   // d within tile
  const int lr = tid >> 4;         // 0..15 (t row; +16 second pass)
  const int lc = (tid & 15) * 4;   // 0..60 (h/d col)
  float accz[4][4] = {};
  float accf[4][4] = {};
  for (int t0 = 0; t0 < S; t0 += 32) {
    #pragma unroll
    for (int rr = lr; rr < 32; rr += 16) {
      const size_t ta = (size_t)(t0 + rr) * BH + (size_t)b * H + h0 + lc;
      *(float4*)&As[rr][lc] = *(const float4*)&Az[ta];
      *(float4*)&Afs[rr][lc] = *(const float4*)&Af[ta];
      const size_t tx = (size_t)(t0 + rr) * (B * D) + (size_t)b * D + d0 + lc;
      *(float4*)&Xs[rr][lc] = *(const float4*)&x[tx];
    }
    __syncthreads();
    #pragma unroll
    for (int k = 0; k < 32; ++k) {
      float4 a4 = *(const float4*)&As[k][tm];
      float4 f4 = *(const float4*)&Afs[k][tm];
      float4 x4 = *(const float4*)&Xs[k][tn];
      float az_[4] = {a4.x, a4.y, a4.z, a4.w};
      float af_[4] = {f4.x, f4.y, f4.z, f4.w};
      float xx[4] = {x4.x, x4.y, x4.z, x4.w};
      #pragma unroll
      for (int i = 0; i < 4; ++i) {
        #pragma unroll
        for (int j = 0; j < 4; ++j) {
          accz[i][j] = fmaf(az_[i], xx[j], accz[i][j]);
          accf[i][j] = fmaf(af_[i], xx[j], accf[i][j]);
        }
      }
    }
    __syncthreads();
  }
  #pragma unroll
  for (int i = 0; i < 4; ++i) {
    const int h = h0 + tm + i;
    const float p0 = P0[b * H + h];
    const size_t row = ((size_t)b * H + h) * D + d0 + tn;
    float4 z0 = *(const float4*)&Z0[row];
    float4 f0 = *(const float4*)&F0[row];
    *(float4*)&Zn[row] = make_float4(
        fmaf(p0, z0.x, accz[i][0]), fmaf(p0, z0.y, accz[i][1]),
        fmaf(p0, z0.z, accz[i][2]), fmaf(p0, z0.w, accz[i][3]));
    *(float4*)&Fn[row] = make_float4(
        fmaf(p0, f0.x, accf[i][0]), fmaf(p0, f0.y, accf[i][1]),
        fmaf(p0, f0.z, accf[i][2]), fmaf(p0, f0.w, accf[i][3]));
  }
}

}  // namespace

extern "C" void kernel_launch(void* const* d_in, const int* in_sizes, int n_in,
                              void* d_out, int out_size, void* d_ws,
                              size_t ws_size, hipStream_t stream) {
  const float* x = (const float*)d_in[0];
  const float* hidden_prev = (const float*)d_in[1];
  const float* Z_state = (const float*)d_in[2];
  const float* F_state = (const float*)d_in[3];
  const float* wz_state = (const float*)d_in[4];
  const float* wf_state = (const float*)d_in[5];
  const float* bz_state = (const float*)d_in[6];
  const float* bf_state = (const float*)d_in[7];
  const float* wm_z = (const float*)d_in[8];
  const float* wm_f = (const float*)d_in[9];
  const float* wv_z = (const float*)d_in[10];
  const float* wv_f = (const float*)d_in[11];
  const float* bias_z = (const float*)d_in[12];
  const float* bias_f = (const float*)d_in[13];

  // Workspace: 3 arrays of S*B*H floats + B*H floats  (~50.5 MB)
  float* ws = (float*)d_ws;
  const size_t SBH = (size_t)S * BH;
  float* ws0 = ws;              // pre_z -> zf -> Az
  float* ws1 = ws + SBH;        // pre_f -> fz -> Af
  float* ws2 = ws + 2 * SBH;    // common
  float* P0 = ws + 3 * SBH;     // [B*H]

  // Output layout (flat f32, reference return order)
  float* out = (float*)d_out;
  float* out_cells = out;                       // S*B*H
  float* out_newcell = out + SBH;               // B*H
  float* out_Zn = out_newcell + BH;             // B*H*D
  float* out_Fn = out_Zn + (size_t)BH * D;      // B*H*D
  float* out_wzn = out_Fn + (size_t)BH * D;     // B*H
  float* out_wfn = out_wzn + BH;
  float* out_bzn = out_wfn + BH;
  float* out_bfn = out_bzn + BH;

  proj_gemm<<<dim3(M1 / 64, H / 64), 256, 0, stream>>>(x, wm_z, wm_f, ws0,
                                                       ws1);
  scan_kernel<<<BH / 256, 256, 0, stream>>>(
      hidden_prev, wz_state, wf_state, bz_state, bf_state, wv_z, wv_f, bias_z,
      bias_f, ws0, ws1, ws2, P0, out_cells, out_newcell, out_wzn, out_wfn,
      out_bzn, out_bfn);
  out_gemm<<<dim3(D / 64, H / 64, B), 256, 0, stream>>>(
      x, ws0, ws1, P0, Z_state, F_state, out_Zn, out_Fn);
}

// Round 2
// 181.540 us; speedup vs baseline: 1.8960x; 1.8960x over previous
//
#include <hip/hip_runtime.h>
#include <math.h>

namespace {

typedef short short8 __attribute__((ext_vector_type(8)));
typedef float floatx4 __attribute__((ext_vector_type(4)));
typedef unsigned int uint32;
typedef unsigned short ushort16;
typedef unsigned long long u64;

constexpr int S = 256, B = 32, D = 512, H = 512;
constexpr int BH = B * H;        // 16384
constexpr int M1 = S * B;        // 8192
constexpr int XN = M1 * D;       // 4194304 elements of x
constexpr int WN = H * D;        // 262144 elements per weight matrix
constexpr int SBH = S * BH;      // 4194304

__device__ __forceinline__ ushort16 f2bf(float f) {
  uint32 x = __float_as_uint(f);
  uint32 r = (x + 0x7fffu + ((x >> 16) & 1u)) >> 16;  // RNE
  return (ushort16)r;
}

__device__ __forceinline__ float fast_sigmoid(float x) {
  float e = __expf(-x);
  return __builtin_amdgcn_rcpf(1.0f + e);
}
__device__ __forceinline__ float fast_tanh(float x) {
  float e = __expf(-2.0f * x);
  return fmaf(2.0f, __builtin_amdgcn_rcpf(1.0f + e), -1.0f);
}

// ---------------------------------------------------------------------------
// Convert x, wm_z, wm_f to bf16 (x is consumed by BOTH gemms).
// ---------------------------------------------------------------------------
__global__ __launch_bounds__(256) void convert_kernel(
    const float* __restrict__ x, const float* __restrict__ wmz,
    const float* __restrict__ wmf, ushort16* __restrict__ xb,
    ushort16* __restrict__ wmzb, ushort16* __restrict__ wmfb) {
  int i = (blockIdx.x * 256 + threadIdx.x) * 8;
  const float* src;
  ushort16* dst;
  int off;
  if (i < XN) {
    src = x; dst = xb; off = i;
  } else if (i < XN + WN) {
    src = wmz; dst = wmzb; off = i - XN;
  } else {
    src = wmf; dst = wmfb; off = i - XN - WN;
  }
  float4 a = *(const float4*)&src[off];
  float4 b = *(const float4*)&src[off + 4];
  uint4 o;
  o.x = (uint32)f2bf(a.x) | ((uint32)f2bf(a.y) << 16);
  o.y = (uint32)f2bf(a.z) | ((uint32)f2bf(a.w) << 16);
  o.z = (uint32)f2bf(b.x) | ((uint32)f2bf(b.y) << 16);
  o.w = (uint32)f2bf(b.z) | ((uint32)f2bf(b.w) << 16);
  *(uint4*)&dst[off] = o;
}

// ---------------------------------------------------------------------------
// Proj GEMM (MFMA): pre[m][h] = sum_d x[m][d]*wm[h][d], dual-B, out float2.
// BM=128, BN=64, BK=64. 4 waves, wave w owns rows [32w,32w+32).
// ---------------------------------------------------------------------------
constexpr int LDA = 72;  // LDS row stride (bf16 el), 144B: 16B-aligned, 2-way banks
__global__ __launch_bounds__(256) void proj_gemm(
    const ushort16* __restrict__ xb, const ushort16* __restrict__ wmzb,
    const ushort16* __restrict__ wmfb, float2* __restrict__ pzf) {
  __shared__ ushort16 As[128 * LDA];
  __shared__ ushort16 Bzs[64 * LDA];
  __shared__ ushort16 Bfs[64 * LDA];
  const int tid = threadIdx.x;
  const int m0 = blockIdx.x * 128;
  const int n0 = blockIdx.y * 64;
  const int w = tid >> 6, l = tid & 63;
  const int lr = l & 15, lg = l >> 4;
  floatx4 accz[2][4], accf[2][4];
#pragma unroll
  for (int m = 0; m < 2; ++m)
#pragma unroll
    for (int n = 0; n < 4; ++n) {
      accz[m][n] = 0;
      accf[m][n] = 0;
    }
  const int sr = tid >> 3;         // 0..31
  const int sc = (tid & 7) * 8;    // 0..56
  for (int k0 = 0; k0 < D; k0 += 64) {
    __syncthreads();
#pragma unroll
    for (int p = 0; p < 4; ++p) {
      int r = sr + 32 * p;
      *(short8*)&As[r * LDA + sc] =
          *(const short8*)&xb[(size_t)(m0 + r) * D + k0 + sc];
    }
#pragma unroll
    for (int p = 0; p < 2; ++p) {
      int r = sr + 32 * p;
      *(short8*)&Bzs[r * LDA + sc] =
          *(const short8*)&wmzb[(size_t)(n0 + r) * D + k0 + sc];
      *(short8*)&Bfs[r * LDA + sc] =
          *(const short8*)&wmfb[(size_t)(n0 + r) * D + k0 + sc];
    }
    __syncthreads();
#pragma unroll
    for (int kk = 0; kk < 2; ++kk) {
      const int kb = kk * 32 + lg * 8;
      short8 a0 = *(const short8*)&As[(32 * w + lr) * LDA + kb];
      short8 a1 = *(const short8*)&As[(32 * w + 16 + lr) * LDA + kb];
#pragma unroll
      for (int n = 0; n < 4; ++n) {
        short8 bz = *(const short8*)&Bzs[(16 * n + lr) * LDA + kb];
        short8 bf = *(const short8*)&Bfs[(16 * n + lr) * LDA + kb];
        accz[0][n] = __builtin_amdgcn_mfma_f32_16x16x32_bf16(a0, bz, accz[0][n], 0, 0, 0);
        accz[1][n] = __builtin_amdgcn_mfma_f32_16x16x32_bf16(a1, bz, accz[1][n], 0, 0, 0);
        accf[0][n] = __builtin_amdgcn_mfma_f32_16x16x32_bf16(a0, bf, accf[0][n], 0, 0, 0);
        accf[1][n] = __builtin_amdgcn_mfma_f32_16x16x32_bf16(a1, bf, accf[1][n], 0, 0, 0);
      }
    }
  }
#pragma unroll
  for (int m = 0; m < 2; ++m)
#pragma unroll
    for (int n = 0; n < 4; ++n)
#pragma unroll
      for (int j = 0; j < 4; ++j) {
        int row = m0 + 32 * w + 16 * m + lg * 4 + j;
        int col = n0 + 16 * n + lr;
        pzf[(size_t)row * H + col] = make_float2(accz[m][n][j], accf[m][n][j]);
      }
}

// ---------------------------------------------------------------------------
// Scan: one thread per (b,h), 16-deep prefetch, fast transcendentals.
// Forward: cells + scalar sensitivities. Backward: recompute zf/fz/common
// from stored cells (exact replay), fold suffix product P, write packed
// bf16 (Az|Af<<16) into azf (upper-half u32 view of pzf; descending-t writes
// only corrupt float2 slots already consumed).
// ---------------------------------------------------------------------------
__global__ __launch_bounds__(64) void scan_kernel(
    const float* __restrict__ hidden_prev, const float* __restrict__ wz0,
    const float* __restrict__ wf0, const float* __restrict__ bz0,
    const float* __restrict__ bf0, const float* __restrict__ wvz_,
    const float* __restrict__ wvf_, const float* __restrict__ bsz_,
    const float* __restrict__ bsf_, float2* __restrict__ pzf,
    uint32* __restrict__ azf, float* __restrict__ P0_out,
    float* __restrict__ out_cells, float* __restrict__ out_newcell,
    float* __restrict__ out_wzn, float* __restrict__ out_wfn,
    float* __restrict__ out_bzn, float* __restrict__ out_bfn) {
  const int bh = blockIdx.x * 64 + threadIdx.x;
  const int h = bh & (H - 1);
  const float hp = hidden_prev[bh];
  float cell = hp;
  float wz = wz0[bh], wf = wf0[bh], bz = bz0[bh], bf = bf0[bh];
  const float wvz = wvz_[h], wvf = wvf_[h], bsz = bsz_[h], bsf = bsf_[h];

  float2 buf[16];
#pragma unroll
  for (int j = 0; j < 16; ++j) buf[j] = pzf[(size_t)j * BH + bh];
  for (int t0 = 0; t0 < S; t0 += 16) {
#pragma unroll
    for (int j = 0; j < 16; ++j) {
      const float2 v = buf[j];
      const int tn = t0 + 16 + j;
      if (tn < S) buf[j] = pzf[(size_t)tn * BH + bh];
      const float z = fast_tanh(fmaf(wvz, cell, v.x + bsz));
      const float f = fast_sigmoid(fmaf(wvf, cell, v.y + bsf));
      const float zf = (1.0f - f) * (1.0f - z * z);
      const float fz = (cell - z) * (1.0f - f) * f;
      const float common = f + zf * wvz + fz * wvf;
      wz = fmaf(common, wz, cell * zf);
      wf = fmaf(common, wf, cell * fz);
      bz = fmaf(common, bz, zf);
      bf = fmaf(common, bf, fz);
      cell = fmaf(f, cell - z, z);
      out_cells[(size_t)(t0 + j) * BH + bh] = cell;
    }
  }
  out_newcell[bh] = cell;
  out_wzn[bh] = wz;
  out_wfn[bh] = wf;
  out_bzn[bh] = bz;
  out_bfn[bh] = bf;

  float P = 1.0f;
  float2 pbuf[16];
  float cbuf[16];
#pragma unroll
  for (int j = 0; j < 16; ++j) {
    const int t = S - 1 - j;
    pbuf[j] = pzf[(size_t)t * BH + bh];
    cbuf[j] = (t >= 1) ? out_cells[(size_t)(t - 1) * BH + bh] : hp;
  }
  for (int t0 = S - 1; t0 > 0; t0 -= 16) {
#pragma unroll
    for (int j = 0; j < 16; ++j) {
      const int t = t0 - j;
      const float2 v = pbuf[j];
      const float cprev = cbuf[j];
      const int tn = t - 16;
      if (tn >= 0) {
        pbuf[j] = pzf[(size_t)tn * BH + bh];
        cbuf[j] = (tn >= 1) ? out_cells[(size_t)(tn - 1) * BH + bh] : hp;
      }
      const float z = fast_tanh(fmaf(wvz, cprev, v.x + bsz));
      const float f = fast_sigmoid(fmaf(wvf, cprev, v.y + bsf));
      const float zf = (1.0f - f) * (1.0f - z * z);
      const float fz = (cprev - z) * (1.0f - f) * f;
      const float common = f + zf * wvz + fz * wvf;
      azf[(size_t)t * BH + bh] =
          (uint32)f2bf(zf * P) | ((uint32)f2bf(fz * P) << 16);
      P *= common;
    }
  }
  P0_out[bh] = P;
}

// ---------------------------------------------------------------------------
// Out GEMM (MFMA): Zn[b][h][d] = P0*Z0 + sum_t Az[t][b][h]*x[t][b][d]
// BM=128(h), BN=64(d), BK=64(t). K-outer LDS tiles (no transpose): fragments
// built via scalar ds_read_u16 + pack. Dual-A (Az,Af) shares the x tile.
// ---------------------------------------------------------------------------
constexpr int LDT = 132;  // Azs/Afs stride (el), 264B: 8B-aligned, 2-way banks
constexpr int LDX = 68;   // Xs stride (el), 136B
__global__ __launch_bounds__(256) void out_gemm(
    const uint32* __restrict__ azf, const ushort16* __restrict__ xb,
    const float* __restrict__ P0, const float* __restrict__ Z0,
    const float* __restrict__ F0, float* __restrict__ Zn,
    float* __restrict__ Fn) {
  __shared__ ushort16 Azs[64 * LDT];
  __shared__ ushort16 Afs[64 * LDT];
  __shared__ ushort16 Xs[64 * LDX];
  const int tid = threadIdx.x;
  const int h0 = blockIdx.x * 128;
  const int d0 = blockIdx.y * 64;
  const int b = blockIdx.z;
  const int w = tid >> 6, l = tid & 63;
  const int lr = l & 15, lg = l >> 4;
  floatx4 accz[2][4], accf[2][4];
#pragma unroll
  for (int m = 0; m < 2; ++m)
#pragma unroll
    for (int n = 0; n < 4; ++n) {
      accz[m][n] = 0;
      accf[m][n] = 0;
    }
  const int at = tid >> 5;          // 0..7
  const int ah = (tid & 31) * 4;    // 0..124
  const int xt = tid >> 3;          // 0..31
  const int xc = (tid & 7) * 8;     // 0..56

  for (int t0 = 0; t0 < S; t0 += 64) {
    __syncthreads();
#pragma unroll
    for (int p = 0; p < 8; ++p) {
      const int t = at + 8 * p;
      const uint4 v =
          *(const uint4*)&azf[(size_t)(t0 + t) * BH + b * H + h0 + ah];
      const int base = t * LDT + ah;
      Azs[base + 0] = (ushort16)(v.x & 0xffffu);
      Afs[base + 0] = (ushort16)(v.x >> 16);
      Azs[base + 1] = (ushort16)(v.y & 0xffffu);
      Afs[base + 1] = (ushort16)(v.y >> 16);
      Azs[base + 2] = (ushort16)(v.z & 0xffffu);
      Afs[base + 2] = (ushort16)(v.z >> 16);
      Azs[base + 3] = (ushort16)(v.w & 0xffffu);
      Afs[base + 3] = (ushort16)(v.w >> 16);
    }
#pragma unroll
    for (int p = 0; p < 2; ++p) {
      const int t = xt + 32 * p;
      const size_t g = (size_t)(t0 + t) * BH + (size_t)b * D + d0 + xc;
      u64 v0 = *(const u64*)&xb[g];
      u64 v1 = *(const u64*)&xb[g + 4];
      *(u64*)&Xs[t * LDX + xc] = v0;
      *(u64*)&Xs[t * LDX + xc + 4] = v1;
    }
    __syncthreads();
#pragma unroll
    for (int kk = 0; kk < 2; ++kk) {
      const int kb = kk * 32 + lg * 8;
      short8 az0, az1, af0, af1, xf[4];
#pragma unroll
      for (int e = 0; e < 8; ++e) {
        const int ro = (kb + e) * LDT;
        az0[e] = (short)Azs[ro + 32 * w + lr];
        az1[e] = (short)Azs[ro + 32 * w + 16 + lr];
        af0[e] = (short)Afs[ro + 32 * w + lr];
        af1[e] = (short)Afs[ro + 32 * w + 16 + lr];
        const int rx = (kb + e) * LDX;
        xf[0][e] = (short)Xs[rx + lr];
        xf[1][e] = (short)Xs[rx + 16 + lr];
        xf[2][e] = (short)Xs[rx + 32 + lr];
        xf[3][e] = (short)Xs[rx + 48 + lr];
      }
#pragma unroll
      for (int n = 0; n < 4; ++n) {
        accz[0][n] = __builtin_amdgcn_mfma_f32_16x16x32_bf16(az0, xf[n], accz[0][n], 0, 0, 0);
        accz[1][n] = __builtin_amdgcn_mfma_f32_16x16x32_bf16(az1, xf[n], accz[1][n], 0, 0, 0);
        accf[0][n] = __builtin_amdgcn_mfma_f32_16x16x32_bf16(af0, xf[n], accf[0][n], 0, 0, 0);
        accf[1][n] = __builtin_amdgcn_mfma_f32_16x16x32_bf16(af1, xf[n], accf[1][n], 0, 0, 0);
      }
    }
  }
#pragma unroll
  for (int m = 0; m < 2; ++m)
#pragma unroll
    for (int j = 0; j < 4; ++j) {
      const int row = h0 + 32 * w + 16 * m + lg * 4 + j;
      const float p0 = P0[b * H + row];
#pragma unroll
      for (int n = 0; n < 4; ++n) {
        const int col = d0 + 16 * n + lr;
        const size_t idx = ((size_t)b * H + row) * D + col;
        Zn[idx] = fmaf(p0, Z0[idx], accz[m][n][j]);
        Fn[idx] = fmaf(p0, F0[idx], accf[m][n][j]);
      }
    }
}

}  // namespace

extern "C" void kernel_launch(void* const* d_in, const int* in_sizes, int n_in,
                              void* d_out, int out_size, void* d_ws,
                              size_t ws_size, hipStream_t stream) {
  const float* x = (const float*)d_in[0];
  const float* hidden_prev = (const float*)d_in[1];
  const float* Z_state = (const float*)d_in[2];
  const float* F_state = (const float*)d_in[3];
  const float* wz_state = (const float*)d_in[4];
  const float* wf_state = (const float*)d_in[5];
  const float* bz_state = (const float*)d_in[6];
  const float* bf_state = (const float*)d_in[7];
  const float* wm_z = (const float*)d_in[8];
  const float* wm_f = (const float*)d_in[9];
  const float* wv_z = (const float*)d_in[10];
  const float* wv_f = (const float*)d_in[11];
  const float* bias_z = (const float*)d_in[12];
  const float* bias_f = (const float*)d_in[13];

  // Workspace layout (~43 MB; round-1 proved >=50.4 MB is available):
  float2* pzf = (float2*)d_ws;                   // [SBH] f32 pre_z|pre_f
  uint32* azf = (uint32*)d_ws + SBH;             // upper-half u32 view: Az|Af
  ushort16* xb = (ushort16*)((float2*)d_ws + SBH);       // [XN] bf16 x
  ushort16* wmzb = xb + XN;                      // [WN]
  ushort16* wmfb = wmzb + WN;                    // [WN]
  float* P0 = (float*)(wmfb + WN);               // [BH]

  float* out = (float*)d_out;
  float* out_cells = out;                        // S*B*H
  float* out_newcell = out + SBH;                // B*H
  float* out_Zn = out_newcell + BH;              // B*H*D
  float* out_Fn = out_Zn + (size_t)BH * D;       // B*H*D
  float* out_wzn = out_Fn + (size_t)BH * D;      // B*H
  float* out_wfn = out_wzn + BH;
  float* out_bzn = out_wfn + BH;
  float* out_bfn = out_bzn + BH;

  convert_kernel<<<(XN + 2 * WN) / 8 / 256, 256, 0, stream>>>(
      x, wm_z, wm_f, xb, wmzb, wmfb);
  proj_gemm<<<dim3(M1 / 128, H / 64), 256, 0, stream>>>(xb, wmzb, wmfb, pzf);
  scan_kernel<<<BH / 64, 64, 0, stream>>>(
      hidden_prev, wz_state, wf_state, bz_state, bf_state, wv_z, wv_f, bias_z,
      bias_f, pzf, azf, P0, out_cells, out_newcell, out_wzn, out_wfn, out_bzn,
      out_bfn);
  out_gemm<<<dim3(H / 128, D / 64, B), 256, 0, stream>>>(
      azf, xb, P0, Z_state, F_state, out_Zn, out_Fn);
}

// Round 3
// 134.692 us; speedup vs baseline: 2.5554x; 1.3478x over previous
//
#include <hip/hip_runtime.h>
#include <math.h>

namespace {

typedef short short8 __attribute__((ext_vector_type(8)));
typedef float floatx4 __attribute__((ext_vector_type(4)));
typedef unsigned int uint32;
typedef unsigned short ushort16;
typedef unsigned long long u64;

constexpr int S = 256, B = 32, D = 512, H = 512;
constexpr int BH = B * H;        // 16384
constexpr int M1 = S * B;        // 8192
constexpr int XN = M1 * D;       // 4194304 elements of x
constexpr int WN = H * D;        // 262144 elements per weight matrix
constexpr int SBH = S * BH;      // 4194304

__device__ __forceinline__ ushort16 f2bf(float f) {
  uint32 x = __float_as_uint(f);
  uint32 r = (x + 0x7fffu + ((x >> 16) & 1u)) >> 16;  // RNE
  return (ushort16)r;
}

__device__ __forceinline__ float fast_sigmoid(float x) {
  float e = __expf(-x);
  return __builtin_amdgcn_rcpf(1.0f + e);
}
__device__ __forceinline__ float fast_tanh(float x) {
  float e = __expf(-2.0f * x);
  return fmaf(2.0f, __builtin_amdgcn_rcpf(1.0f + e), -1.0f);
}

// ---------------------------------------------------------------------------
// Convert x, wm_z, wm_f to bf16 (x is consumed by BOTH gemms).
// ---------------------------------------------------------------------------
__global__ __launch_bounds__(256) void convert_kernel(
    const float* __restrict__ x, const float* __restrict__ wmz,
    const float* __restrict__ wmf, ushort16* __restrict__ xb,
    ushort16* __restrict__ wmzb, ushort16* __restrict__ wmfb) {
  int i = (blockIdx.x * 256 + threadIdx.x) * 8;
  const float* src;
  ushort16* dst;
  int off;
  if (i < XN) {
    src = x; dst = xb; off = i;
  } else if (i < XN + WN) {
    src = wmz; dst = wmzb; off = i - XN;
  } else {
    src = wmf; dst = wmfb; off = i - XN - WN;
  }
  float4 a = *(const float4*)&src[off];
  float4 b = *(const float4*)&src[off + 4];
  uint4 o;
  o.x = (uint32)f2bf(a.x) | ((uint32)f2bf(a.y) << 16);
  o.y = (uint32)f2bf(a.z) | ((uint32)f2bf(a.w) << 16);
  o.z = (uint32)f2bf(b.x) | ((uint32)f2bf(b.y) << 16);
  o.w = (uint32)f2bf(b.z) | ((uint32)f2bf(b.w) << 16);
  *(uint4*)&dst[off] = o;
}

// ---------------------------------------------------------------------------
// Proj GEMM (MFMA): pre[m][h] = sum_d x[m][d]*wm[h][d], dual-B, out float2.
// BM=128, BN=64, BK=64. 4 waves, wave w owns rows [32w,32w+32).
// ---------------------------------------------------------------------------
constexpr int LDA = 72;  // LDS row stride (bf16 el), 144B: 16B-aligned, 2-way banks
__global__ __launch_bounds__(256) void proj_gemm(
    const ushort16* __restrict__ xb, const ushort16* __restrict__ wmzb,
    const ushort16* __restrict__ wmfb, float2* __restrict__ pzf) {
  __shared__ ushort16 As[128 * LDA];
  __shared__ ushort16 Bzs[64 * LDA];
  __shared__ ushort16 Bfs[64 * LDA];
  const int tid = threadIdx.x;
  const int m0 = blockIdx.x * 128;
  const int n0 = blockIdx.y * 64;
  const int w = tid >> 6, l = tid & 63;
  const int lr = l & 15, lg = l >> 4;
  floatx4 accz[2][4], accf[2][4];
#pragma unroll
  for (int m = 0; m < 2; ++m)
#pragma unroll
    for (int n = 0; n < 4; ++n) {
      accz[m][n] = 0;
      accf[m][n] = 0;
    }
  const int sr = tid >> 3;         // 0..31
  const int sc = (tid & 7) * 8;    // 0..56
  for (int k0 = 0; k0 < D; k0 += 64) {
    __syncthreads();
#pragma unroll
    for (int p = 0; p < 4; ++p) {
      int r = sr + 32 * p;
      *(short8*)&As[r * LDA + sc] =
          *(const short8*)&xb[(size_t)(m0 + r) * D + k0 + sc];
    }
#pragma unroll
    for (int p = 0; p < 2; ++p) {
      int r = sr + 32 * p;
      *(short8*)&Bzs[r * LDA + sc] =
          *(const short8*)&wmzb[(size_t)(n0 + r) * D + k0 + sc];
      *(short8*)&Bfs[r * LDA + sc] =
          *(const short8*)&wmfb[(size_t)(n0 + r) * D + k0 + sc];
    }
    __syncthreads();
#pragma unroll
    for (int kk = 0; kk < 2; ++kk) {
      const int kb = kk * 32 + lg * 8;
      short8 a0 = *(const short8*)&As[(32 * w + lr) * LDA + kb];
      short8 a1 = *(const short8*)&As[(32 * w + 16 + lr) * LDA + kb];
#pragma unroll
      for (int n = 0; n < 4; ++n) {
        short8 bz = *(const short8*)&Bzs[(16 * n + lr) * LDA + kb];
        short8 bf = *(const short8*)&Bfs[(16 * n + lr) * LDA + kb];
        accz[0][n] = __builtin_amdgcn_mfma_f32_16x16x32_bf16(a0, bz, accz[0][n], 0, 0, 0);
        accz[1][n] = __builtin_amdgcn_mfma_f32_16x16x32_bf16(a1, bz, accz[1][n], 0, 0, 0);
        accf[0][n] = __builtin_amdgcn_mfma_f32_16x16x32_bf16(a0, bf, accf[0][n], 0, 0, 0);
        accf[1][n] = __builtin_amdgcn_mfma_f32_16x16x32_bf16(a1, bf, accf[1][n], 0, 0, 0);
      }
    }
  }
#pragma unroll
  for (int m = 0; m < 2; ++m)
#pragma unroll
    for (int n = 0; n < 4; ++n)
#pragma unroll
      for (int j = 0; j < 4; ++j) {
        int row = m0 + 32 * w + 16 * m + lg * 4 + j;
        int col = n0 + 16 * n + lr;
        pzf[(size_t)row * H + col] = make_float2(accz[m][n][j], accf[m][n][j]);
      }
}

// ---------------------------------------------------------------------------
// Scan: one thread per (b,h), 16-deep prefetch, fast transcendentals.
// __launch_bounds__(64, 1): occupancy is capped at 1 wave/CU by the grid
// anyway (16384 chains = 256 waves on 256 CUs), so let the register
// allocator use the full VGPR file — round-2's (64) default capped VGPRs
// at 64 and spilled the prefetch buffers to scratch (545 cyc/step).
// ---------------------------------------------------------------------------
__global__ __launch_bounds__(64, 1) void scan_kernel(
    const float* __restrict__ hidden_prev, const float* __restrict__ wz0,
    const float* __restrict__ wf0, const float* __restrict__ bz0,
    const float* __restrict__ bf0, const float* __restrict__ wvz_,
    const float* __restrict__ wvf_, const float* __restrict__ bsz_,
    const float* __restrict__ bsf_, float2* __restrict__ pzf,
    uint32* __restrict__ azf, float* __restrict__ P0_out,
    float* __restrict__ out_cells, float* __restrict__ out_newcell,
    float* __restrict__ out_wzn, float* __restrict__ out_wfn,
    float* __restrict__ out_bzn, float* __restrict__ out_bfn) {
  const int bh = blockIdx.x * 64 + threadIdx.x;
  const int h = bh & (H - 1);
  const float hp = hidden_prev[bh];
  float cell = hp;
  float wz = wz0[bh], wf = wf0[bh], bz = bz0[bh], bf = bf0[bh];
  const float wvz = wvz_[h], wvf = wvf_[h], bsz = bsz_[h], bsf = bsf_[h];

  float2 buf[16];
#pragma unroll
  for (int j = 0; j < 16; ++j) buf[j] = pzf[(size_t)j * BH + bh];
  for (int t0 = 0; t0 < S; t0 += 16) {
#pragma unroll
    for (int j = 0; j < 16; ++j) {
      const float2 v = buf[j];
      int tn = t0 + 16 + j;
      tn = (tn < S) ? tn : (S - 1);              // clamped, unconditional
      buf[j] = pzf[(size_t)tn * BH + bh];
      const float z = fast_tanh(fmaf(wvz, cell, v.x + bsz));
      const float f = fast_sigmoid(fmaf(wvf, cell, v.y + bsf));
      const float zf = (1.0f - f) * (1.0f - z * z);
      const float fz = (cell - z) * (1.0f - f) * f;
      const float common = f + zf * wvz + fz * wvf;
      wz = fmaf(common, wz, cell * zf);
      wf = fmaf(common, wf, cell * fz);
      bz = fmaf(common, bz, zf);
      bf = fmaf(common, bf, fz);
      cell = fmaf(f, cell - z, z);
      out_cells[(size_t)(t0 + j) * BH + bh] = cell;
    }
  }
  out_newcell[bh] = cell;
  out_wzn[bh] = wz;
  out_wfn[bh] = wf;
  out_bzn[bh] = bz;
  out_bfn[bh] = bf;

  float P = 1.0f;
  float2 pbuf[16];
  float cbuf[16];
#pragma unroll
  for (int j = 0; j < 16; ++j) {
    const int t = S - 1 - j;
    pbuf[j] = pzf[(size_t)t * BH + bh];
    cbuf[j] = (t >= 1) ? out_cells[(size_t)(t - 1) * BH + bh] : hp;
  }
  for (int t0 = S - 1; t0 > 0; t0 -= 16) {
#pragma unroll
    for (int j = 0; j < 16; ++j) {
      const int t = t0 - j;
      const float2 v = pbuf[j];
      const float cprev = cbuf[j];
      int tn = t - 16;
      tn = (tn >= 0) ? tn : 0;                   // clamped, unconditional
      pbuf[j] = pzf[(size_t)tn * BH + bh];
      const int tc = (tn >= 1) ? (tn - 1) : 0;
      cbuf[j] = (tn >= 1) ? out_cells[(size_t)tc * BH + bh] : hp;
      const float z = fast_tanh(fmaf(wvz, cprev, v.x + bsz));
      const float f = fast_sigmoid(fmaf(wvf, cprev, v.y + bsf));
      const float zf = (1.0f - f) * (1.0f - z * z);
      const float fz = (cprev - z) * (1.0f - f) * f;
      const float common = f + zf * wvz + fz * wvf;
      azf[(size_t)t * BH + bh] =
          (uint32)f2bf(zf * P) | ((uint32)f2bf(fz * P) << 16);
      P *= common;
    }
  }
  P0_out[bh] = P;
}

// ---------------------------------------------------------------------------
// Out GEMM (MFMA): Zn[b][h][d] = P0*Z0 + sum_t Az[t][b][h]*x[t][b][d]
// BM=128(h), BN=64(d), BK=64(t). K-outer LDS tiles (no transpose): fragments
// built via scalar ds_read_u16 + pack. Dual-A (Az,Af) shares the x tile.
// ---------------------------------------------------------------------------
constexpr int LDT = 132;  // Azs/Afs stride (el), 264B: 8B-aligned, 2-way banks
constexpr int LDX = 68;   // Xs stride (el), 136B
__global__ __launch_bounds__(256) void out_gemm(
    const uint32* __restrict__ azf, const ushort16* __restrict__ xb,
    const float* __restrict__ P0, const float* __restrict__ Z0,
    const float* __restrict__ F0, float* __restrict__ Zn,
    float* __restrict__ Fn) {
  __shared__ ushort16 Azs[64 * LDT];
  __shared__ ushort16 Afs[64 * LDT];
  __shared__ ushort16 Xs[64 * LDX];
  const int tid = threadIdx.x;
  const int h0 = blockIdx.x * 128;
  const int d0 = blockIdx.y * 64;
  const int b = blockIdx.z;
  const int w = tid >> 6, l = tid & 63;
  const int lr = l & 15, lg = l >> 4;
  floatx4 accz[2][4], accf[2][4];
#pragma unroll
  for (int m = 0; m < 2; ++m)
#pragma unroll
    for (int n = 0; n < 4; ++n) {
      accz[m][n] = 0;
      accf[m][n] = 0;
    }
  const int at = tid >> 5;          // 0..7
  const int ah = (tid & 31) * 4;    // 0..124
  const int xt = tid >> 3;          // 0..31
  const int xc = (tid & 7) * 8;     // 0..56

  for (int t0 = 0; t0 < S; t0 += 64) {
    __syncthreads();
#pragma unroll
    for (int p = 0; p < 8; ++p) {
      const int t = at + 8 * p;
      const uint4 v =
          *(const uint4*)&azf[(size_t)(t0 + t) * BH + b * H + h0 + ah];
      const int base = t * LDT + ah;
      Azs[base + 0] = (ushort16)(v.x & 0xffffu);
      Afs[base + 0] = (ushort16)(v.x >> 16);
      Azs[base + 1] = (ushort16)(v.y & 0xffffu);
      Afs[base + 1] = (ushort16)(v.y >> 16);
      Azs[base + 2] = (ushort16)(v.z & 0xffffu);
      Afs[base + 2] = (ushort16)(v.z >> 16);
      Azs[base + 3] = (ushort16)(v.w & 0xffffu);
      Afs[base + 3] = (ushort16)(v.w >> 16);
    }
#pragma unroll
    for (int p = 0; p < 2; ++p) {
      const int t = xt + 32 * p;
      const size_t g = (size_t)(t0 + t) * BH + (size_t)b * D + d0 + xc;
      u64 v0 = *(const u64*)&xb[g];
      u64 v1 = *(const u64*)&xb[g + 4];
      *(u64*)&Xs[t * LDX + xc] = v0;
      *(u64*)&Xs[t * LDX + xc + 4] = v1;
    }
    __syncthreads();
#pragma unroll
    for (int kk = 0; kk < 2; ++kk) {
      const int kb = kk * 32 + lg * 8;
      short8 az0, az1, af0, af1, xf[4];
#pragma unroll
      for (int e = 0; e < 8; ++e) {
        const int ro = (kb + e) * LDT;
        az0[e] = (short)Azs[ro + 32 * w + lr];
        az1[e] = (short)Azs[ro + 32 * w + 16 + lr];
        af0[e] = (short)Afs[ro + 32 * w + lr];
        af1[e] = (short)Afs[ro + 32 * w + 16 + lr];
        const int rx = (kb + e) * LDX;
        xf[0][e] = (short)Xs[rx + lr];
        xf[1][e] = (short)Xs[rx + 16 + lr];
        xf[2][e] = (short)Xs[rx + 32 + lr];
        xf[3][e] = (short)Xs[rx + 48 + lr];
      }
#pragma unroll
      for (int n = 0; n < 4; ++n) {
        accz[0][n] = __builtin_amdgcn_mfma_f32_16x16x32_bf16(az0, xf[n], accz[0][n], 0, 0, 0);
        accz[1][n] = __builtin_amdgcn_mfma_f32_16x16x32_bf16(az1, xf[n], accz[1][n], 0, 0, 0);
        accf[0][n] = __builtin_amdgcn_mfma_f32_16x16x32_bf16(af0, xf[n], accf[0][n], 0, 0, 0);
        accf[1][n] = __builtin_amdgcn_mfma_f32_16x16x32_bf16(af1, xf[n], accf[1][n], 0, 0, 0);
      }
    }
  }
#pragma unroll
  for (int m = 0; m < 2; ++m)
#pragma unroll
    for (int j = 0; j < 4; ++j) {
      const int row = h0 + 32 * w + 16 * m + lg * 4 + j;
      const float p0 = P0[b * H + row];
#pragma unroll
      for (int n = 0; n < 4; ++n) {
        const int col = d0 + 16 * n + lr;
        const size_t idx = ((size_t)b * H + row) * D + col;
        Zn[idx] = fmaf(p0, Z0[idx], accz[m][n][j]);
        Fn[idx] = fmaf(p0, F0[idx], accf[m][n][j]);
      }
    }
}

}  // namespace

extern "C" void kernel_launch(void* const* d_in, const int* in_sizes, int n_in,
                              void* d_out, int out_size, void* d_ws,
                              size_t ws_size, hipStream_t stream) {
  const float* x = (const float*)d_in[0];
  const float* hidden_prev = (const float*)d_in[1];
  const float* Z_state = (const float*)d_in[2];
  const float* F_state = (const float*)d_in[3];
  const float* wz_state = (const float*)d_in[4];
  const float* wf_state = (const float*)d_in[5];
  const float* bz_state = (const float*)d_in[6];
  const float* bf_state = (const float*)d_in[7];
  const float* wm_z = (const float*)d_in[8];
  const float* wm_f = (const float*)d_in[9];
  const float* wv_z = (const float*)d_in[10];
  const float* wv_f = (const float*)d_in[11];
  const float* bias_z = (const float*)d_in[12];
  const float* bias_f = (const float*)d_in[13];

  // Workspace layout (~43 MB):
  float2* pzf = (float2*)d_ws;                   // [SBH] f32 pre_z|pre_f
  uint32* azf = (uint32*)d_ws + SBH;             // upper-half u32 view: Az|Af
  ushort16* xb = (ushort16*)((float2*)d_ws + SBH);       // [XN] bf16 x
  ushort16* wmzb = xb + XN;                      // [WN]
  ushort16* wmfb = wmzb + WN;                    // [WN]
  float* P0 = (float*)(wmfb + WN);               // [BH]

  float* out = (float*)d_out;
  float* out_cells = out;                        // S*B*H
  float* out_newcell = out + SBH;                // B*H
  float* out_Zn = out_newcell + BH;              // B*H*D
  float* out_Fn = out_Zn + (size_t)BH * D;       // B*H*D
  float* out_wzn = out_Fn + (size_t)BH * D;      // B*H
  float* out_wfn = out_wzn + BH;
  float* out_bzn = out_wfn + BH;
  float* out_bfn = out_bzn + BH;

  convert_kernel<<<(XN + 2 * WN) / 8 / 256, 256, 0, stream>>>(
      x, wm_z, wm_f, xb, wmzb, wmfb);
  proj_gemm<<<dim3(M1 / 128, H / 64), 256, 0, stream>>>(xb, wmzb, wmfb, pzf);
  scan_kernel<<<BH / 64, 64, 0, stream>>>(
      hidden_prev, wz_state, wf_state, bz_state, bf_state, wv_z, wv_f, bias_z,
      bias_f, pzf, azf, P0, out_cells, out_newcell, out_wzn, out_wfn, out_bzn,
      out_bfn);
  out_gemm<<<dim3(H / 128, D / 64, B), 256, 0, stream>>>(
      azf, xb, P0, Z_state, F_state, out_Zn, out_Fn);
}

// Round 4
// 114.501 us; speedup vs baseline: 3.0060x; 1.1763x over previous
//
#include <hip/hip_runtime.h>
#include <math.h>

namespace {

typedef short short8 __attribute__((ext_vector_type(8)));
typedef float floatx4 __attribute__((ext_vector_type(4)));
typedef unsigned int uint32;
typedef unsigned short ushort16;
typedef unsigned long long u64;

constexpr int S = 256, B = 32, D = 512, H = 512;
constexpr int BH = B * H;        // 16384
constexpr int M1 = S * B;        // 8192
constexpr int XN = M1 * D;       // 4194304 elements of x
constexpr int WN = H * D;        // 262144 elements per weight matrix
constexpr int SBH = S * BH;      // 4194304

__device__ __forceinline__ uint32 f2bf(float f) {
  uint32 x = __float_as_uint(f);
  return (x + 0x7fffu + ((x >> 16) & 1u)) >> 16;  // RNE
}

__device__ __forceinline__ float fast_sigmoid(float x) {
  float e = __expf(-x);
  return __builtin_amdgcn_rcpf(1.0f + e);
}
__device__ __forceinline__ float fast_tanh(float x) {
  float e = __expf(-2.0f * x);
  return fmaf(2.0f, __builtin_amdgcn_rcpf(1.0f + e), -1.0f);
}

// ---------------------------------------------------------------------------
// Convert x, wm_z, wm_f to bf16 (x is consumed by BOTH gemms).
// ---------------------------------------------------------------------------
__global__ __launch_bounds__(256) void convert_kernel(
    const float* __restrict__ x, const float* __restrict__ wmz,
    const float* __restrict__ wmf, ushort16* __restrict__ xb,
    ushort16* __restrict__ wmzb, ushort16* __restrict__ wmfb) {
  int i = (blockIdx.x * 256 + threadIdx.x) * 8;
  const float* src;
  ushort16* dst;
  int off;
  if (i < XN) {
    src = x; dst = xb; off = i;
  } else if (i < XN + WN) {
    src = wmz; dst = wmzb; off = i - XN;
  } else {
    src = wmf; dst = wmfb; off = i - XN - WN;
  }
  float4 a = *(const float4*)&src[off];
  float4 b = *(const float4*)&src[off + 4];
  uint4 o;
  o.x = f2bf(a.x) | (f2bf(a.y) << 16);
  o.y = f2bf(a.z) | (f2bf(a.w) << 16);
  o.z = f2bf(b.x) | (f2bf(b.y) << 16);
  o.w = f2bf(b.z) | (f2bf(b.w) << 16);
  *(uint4*)&dst[off] = o;
}

// ---------------------------------------------------------------------------
// Proj GEMM (MFMA): pre[m][h] = sum_d x[m][d]*wm[h][d], dual-B, out float2.
// BM=128, BN=64, BK=64. 4 waves, wave w owns rows [32w,32w+32).
// ---------------------------------------------------------------------------
constexpr int LDA = 72;  // LDS row stride (bf16 el)
__global__ __launch_bounds__(256) void proj_gemm(
    const ushort16* __restrict__ xb, const ushort16* __restrict__ wmzb,
    const ushort16* __restrict__ wmfb, float2* __restrict__ pzf) {
  __shared__ ushort16 As[128 * LDA];
  __shared__ ushort16 Bzs[64 * LDA];
  __shared__ ushort16 Bfs[64 * LDA];
  const int tid = threadIdx.x;
  const int m0 = blockIdx.x * 128;
  const int n0 = blockIdx.y * 64;
  const int w = tid >> 6, l = tid & 63;
  const int lr = l & 15, lg = l >> 4;
  floatx4 accz[2][4], accf[2][4];
#pragma unroll
  for (int m = 0; m < 2; ++m)
#pragma unroll
    for (int n = 0; n < 4; ++n) {
      accz[m][n] = 0;
      accf[m][n] = 0;
    }
  const int sr = tid >> 3;         // 0..31
  const int sc = (tid & 7) * 8;    // 0..56
  for (int k0 = 0; k0 < D; k0 += 64) {
    __syncthreads();
#pragma unroll
    for (int p = 0; p < 4; ++p) {
      int r = sr + 32 * p;
      *(short8*)&As[r * LDA + sc] =
          *(const short8*)&xb[(size_t)(m0 + r) * D + k0 + sc];
    }
#pragma unroll
    for (int p = 0; p < 2; ++p) {
      int r = sr + 32 * p;
      *(short8*)&Bzs[r * LDA + sc] =
          *(const short8*)&wmzb[(size_t)(n0 + r) * D + k0 + sc];
      *(short8*)&Bfs[r * LDA + sc] =
          *(const short8*)&wmfb[(size_t)(n0 + r) * D + k0 + sc];
    }
    __syncthreads();
#pragma unroll
    for (int kk = 0; kk < 2; ++kk) {
      const int kb = kk * 32 + lg * 8;
      short8 a0 = *(const short8*)&As[(32 * w + lr) * LDA + kb];
      short8 a1 = *(const short8*)&As[(32 * w + 16 + lr) * LDA + kb];
#pragma unroll
      for (int n = 0; n < 4; ++n) {
        short8 bz = *(const short8*)&Bzs[(16 * n + lr) * LDA + kb];
        short8 bf = *(const short8*)&Bfs[(16 * n + lr) * LDA + kb];
        accz[0][n] = __builtin_amdgcn_mfma_f32_16x16x32_bf16(a0, bz, accz[0][n], 0, 0, 0);
        accz[1][n] = __builtin_amdgcn_mfma_f32_16x16x32_bf16(a1, bz, accz[1][n], 0, 0, 0);
        accf[0][n] = __builtin_amdgcn_mfma_f32_16x16x32_bf16(a0, bf, accf[0][n], 0, 0, 0);
        accf[1][n] = __builtin_amdgcn_mfma_f32_16x16x32_bf16(a1, bf, accf[1][n], 0, 0, 0);
      }
    }
  }
#pragma unroll
  for (int m = 0; m < 2; ++m)
#pragma unroll
    for (int n = 0; n < 4; ++n)
#pragma unroll
      for (int j = 0; j < 4; ++j) {
        int row = m0 + 32 * w + 16 * m + lg * 4 + j;
        int col = n0 + 16 * n + lr;
        pzf[(size_t)row * H + col] = make_float2(accz[m][n][j], accf[m][n][j]);
      }
}

// ---------------------------------------------------------------------------
// Scan forward only. One thread per (b,h). 16-deep prefetch in NAMED float2
// registers (no arrays -> regalloc cannot send them to scratch).
// Per step: compute gates + scalar sensitivities; store cell ([t][bh], 4B
// coalesced) and {packed bf16 (zf|fz), f32 common} as ONE 8B store written
// in-place into the just-consumed pzf slot. No clamped tail loads: the last
// 16-step group issues no prefetch, so every load reads t >= current_store_t
// + 16 (provably disjoint; no aliasing stalls).
// Suffix products moved to a parallel kernel.
// ---------------------------------------------------------------------------
#define STEP_BODY(J)                                                       \
    const float z = fast_tanh(fmaf(wvz, cell, pzv));                       \
    const float f = fast_sigmoid(fmaf(wvf, cell, pfv));                    \
    const float zf = (1.0f - f) * (1.0f - z * z);                          \
    const float fz = (cell - z) * (1.0f - f) * f;                          \
    const float common = f + zf * wvz + fz * wvf;                          \
    wz = fmaf(common, wz, cell * zf);                                      \
    wf = fmaf(common, wf, cell * fz);                                      \
    bz = fmaf(common, bz, zf);                                             \
    bf = fmaf(common, bf, fz);                                             \
    cell = fmaf(f, cell - z, z);                                           \
    const size_t ti = (size_t)(t0 + (J)) * BH;                             \
    cp[ti] = cell;                                                         \
    pz[ti] = make_float2(                                                  \
        __uint_as_float(f2bf(zf) | (f2bf(fz) << 16)), common);

#define STEP_L(J, Q)                                                       \
  {                                                                        \
    const float pzv = Q.x + bsz, pfv = Q.y + bsf;                          \
    Q = pz[(size_t)(t0 + 16 + (J)) * BH];                                  \
    STEP_BODY(J)                                                           \
  }

#define STEP_N(J, Q)                                                       \
  {                                                                        \
    const float pzv = Q.x + bsz, pfv = Q.y + bsf;                          \
    STEP_BODY(J)                                                           \
  }

__global__ __launch_bounds__(64, 1) void scan_fwd(
    const float* __restrict__ hidden_prev, const float* __restrict__ wz0,
    const float* __restrict__ wf0, const float* __restrict__ bz0,
    const float* __restrict__ bf0, const float* __restrict__ wvz_,
    const float* __restrict__ wvf_, const float* __restrict__ bsz_,
    const float* __restrict__ bsf_, float2* pzf_,
    float* __restrict__ out_cells, float* __restrict__ out_newcell,
    float* __restrict__ out_wzn, float* __restrict__ out_wfn,
    float* __restrict__ out_bzn, float* __restrict__ out_bfn) {
  const int bh = blockIdx.x * 64 + threadIdx.x;
  const int h = bh & (H - 1);
  float cell = hidden_prev[bh];
  float wz = wz0[bh], wf = wf0[bh], bz = bz0[bh], bf = bf0[bh];
  const float wvz = wvz_[h], wvf = wvf_[h], bsz = bsz_[h], bsf = bsf_[h];
  float2* pz = pzf_ + bh;          // loads and in-place stores, stride BH
  float* cp = out_cells + bh;

  float2 q0 = pz[(size_t)0 * BH], q1 = pz[(size_t)1 * BH];
  float2 q2 = pz[(size_t)2 * BH], q3 = pz[(size_t)3 * BH];
  float2 q4 = pz[(size_t)4 * BH], q5 = pz[(size_t)5 * BH];
  float2 q6 = pz[(size_t)6 * BH], q7 = pz[(size_t)7 * BH];
  float2 q8 = pz[(size_t)8 * BH], q9 = pz[(size_t)9 * BH];
  float2 q10 = pz[(size_t)10 * BH], q11 = pz[(size_t)11 * BH];
  float2 q12 = pz[(size_t)12 * BH], q13 = pz[(size_t)13 * BH];
  float2 q14 = pz[(size_t)14 * BH], q15 = pz[(size_t)15 * BH];

  for (int t0 = 0; t0 < S - 16; t0 += 16) {
    STEP_L(0, q0)  STEP_L(1, q1)  STEP_L(2, q2)  STEP_L(3, q3)
    STEP_L(4, q4)  STEP_L(5, q5)  STEP_L(6, q6)  STEP_L(7, q7)
    STEP_L(8, q8)  STEP_L(9, q9)  STEP_L(10, q10) STEP_L(11, q11)
    STEP_L(12, q12) STEP_L(13, q13) STEP_L(14, q14) STEP_L(15, q15)
  }
  {
    const int t0 = S - 16;
    STEP_N(0, q0)  STEP_N(1, q1)  STEP_N(2, q2)  STEP_N(3, q3)
    STEP_N(4, q4)  STEP_N(5, q5)  STEP_N(6, q6)  STEP_N(7, q7)
    STEP_N(8, q8)  STEP_N(9, q9)  STEP_N(10, q10) STEP_N(11, q11)
    STEP_N(12, q12) STEP_N(13, q13) STEP_N(14, q14) STEP_N(15, q15)
  }
  out_newcell[bh] = cell;
  out_wzn[bh] = wz;
  out_wfn[bh] = wf;
  out_bzn[bh] = bz;
  out_bfn[bh] = bf;
}

// ---------------------------------------------------------------------------
// Suffix products (parallel replacement for the serial backward pass).
// Block: 1024 threads = 16 waves; wave c owns t-chunk [16c, 16c+16) for 64
// consecutive chains. Phase 1: load 16 {zffz, common} slots into regs,
// local product -> LDS. Phase 2: cross-chunk exclusive suffix product.
// Phase 3: walk chunk descending, azf[t] = pack(zf*P, fz*P), P *= common.
// All global accesses 256/512B-coalesced per wave.
// ---------------------------------------------------------------------------
__global__ __launch_bounds__(1024) void suffix_kernel(
    const float2* __restrict__ pzfc, uint32* __restrict__ azf,
    float* __restrict__ P0_out) {
  __shared__ float prods[16][65];
  const int bh_l = threadIdx.x & 63;
  const int c = threadIdx.x >> 6;
  const int bh = blockIdx.x * 64 + bh_l;
  const float2* p = pzfc + bh;
  float2 v[16];
#pragma unroll
  for (int i = 0; i < 16; ++i) v[i] = p[(size_t)(c * 16 + i) * BH];
  float L = 1.0f;
#pragma unroll
  for (int i = 0; i < 16; ++i) L *= v[i].y;
  prods[c][bh_l] = L;
  __syncthreads();
  float run = 1.0f;
#pragma unroll
  for (int cc = 1; cc < 16; ++cc)
    if (cc > c) run *= prods[cc][bh_l];
  uint32* az = azf + bh;
#pragma unroll
  for (int i = 15; i >= 0; --i) {
    const int t = c * 16 + i;
    const uint32 w32 = __float_as_uint(v[i].x);
    const float zf = __uint_as_float((w32 & 0xffffu) << 16);
    const float fz = __uint_as_float(w32 & 0xffff0000u);
    az[(size_t)t * BH] = f2bf(zf * run) | (f2bf(fz * run) << 16);
    run *= v[i].y;
  }
  if (c == 0) P0_out[bh] = run;
}

// ---------------------------------------------------------------------------
// Out GEMM (MFMA): Zn[b][h][d] = P0*Z0 + sum_t Az[t][b][h]*x[t][b][d]
// ---------------------------------------------------------------------------
constexpr int LDT = 132;
constexpr int LDX = 68;
__global__ __launch_bounds__(256) void out_gemm(
    const uint32* __restrict__ azf, const ushort16* __restrict__ xb,
    const float* __restrict__ P0, const float* __restrict__ Z0,
    const float* __restrict__ F0, float* __restrict__ Zn,
    float* __restrict__ Fn) {
  __shared__ ushort16 Azs[64 * LDT];
  __shared__ ushort16 Afs[64 * LDT];
  __shared__ ushort16 Xs[64 * LDX];
  const int tid = threadIdx.x;
  const int h0 = blockIdx.x * 128;
  const int d0 = blockIdx.y * 64;
  const int b = blockIdx.z;
  const int w = tid >> 6, l = tid & 63;
  const int lr = l & 15, lg = l >> 4;
  floatx4 accz[2][4], accf[2][4];
#pragma unroll
  for (int m = 0; m < 2; ++m)
#pragma unroll
    for (int n = 0; n < 4; ++n) {
      accz[m][n] = 0;
      accf[m][n] = 0;
    }
  const int at = tid >> 5;
  const int ah = (tid & 31) * 4;
  const int xt = tid >> 3;
  const int xc = (tid & 7) * 8;

  for (int t0 = 0; t0 < S; t0 += 64) {
    __syncthreads();
#pragma unroll
    for (int p = 0; p < 8; ++p) {
      const int t = at + 8 * p;
      const uint4 v =
          *(const uint4*)&azf[(size_t)(t0 + t) * BH + b * H + h0 + ah];
      const int base = t * LDT + ah;
      Azs[base + 0] = (ushort16)(v.x & 0xffffu);
      Afs[base + 0] = (ushort16)(v.x >> 16);
      Azs[base + 1] = (ushort16)(v.y & 0xffffu);
      Afs[base + 1] = (ushort16)(v.y >> 16);
      Azs[base + 2] = (ushort16)(v.z & 0xffffu);
      Afs[base + 2] = (ushort16)(v.z >> 16);
      Azs[base + 3] = (ushort16)(v.w & 0xffffu);
      Afs[base + 3] = (ushort16)(v.w >> 16);
    }
#pragma unroll
    for (int p = 0; p < 2; ++p) {
      const int t = xt + 32 * p;
      const size_t g = (size_t)(t0 + t) * BH + (size_t)b * D + xc + d0;
      u64 v0 = *(const u64*)&xb[g];
      u64 v1 = *(const u64*)&xb[g + 4];
      *(u64*)&Xs[t * LDX + xc] = v0;
      *(u64*)&Xs[t * LDX + xc + 4] = v1;
    }
    __syncthreads();
#pragma unroll
    for (int kk = 0; kk < 2; ++kk) {
      const int kb = kk * 32 + lg * 8;
      short8 az0, az1, af0, af1, xf[4];
#pragma unroll
      for (int e = 0; e < 8; ++e) {
        const int ro = (kb + e) * LDT;
        az0[e] = (short)Azs[ro + 32 * w + lr];
        az1[e] = (short)Azs[ro + 32 * w + 16 + lr];
        af0[e] = (short)Afs[ro + 32 * w + lr];
        af1[e] = (short)Afs[ro + 32 * w + 16 + lr];
        const int rx = (kb + e) * LDX;
        xf[0][e] = (short)Xs[rx + lr];
        xf[1][e] = (short)Xs[rx + 16 + lr];
        xf[2][e] = (short)Xs[rx + 32 + lr];
        xf[3][e] = (short)Xs[rx + 48 + lr];
      }
#pragma unroll
      for (int n = 0; n < 4; ++n) {
        accz[0][n] = __builtin_amdgcn_mfma_f32_16x16x32_bf16(az0, xf[n], accz[0][n], 0, 0, 0);
        accz[1][n] = __builtin_amdgcn_mfma_f32_16x16x32_bf16(az1, xf[n], accz[1][n], 0, 0, 0);
        accf[0][n] = __builtin_amdgcn_mfma_f32_16x16x32_bf16(af0, xf[n], accf[0][n], 0, 0, 0);
        accf[1][n] = __builtin_amdgcn_mfma_f32_16x16x32_bf16(af1, xf[n], accf[1][n], 0, 0, 0);
      }
    }
  }
#pragma unroll
  for (int m = 0; m < 2; ++m)
#pragma unroll
    for (int j = 0; j < 4; ++j) {
      const int row = h0 + 32 * w + 16 * m + lg * 4 + j;
      const float p0 = P0[b * H + row];
#pragma unroll
      for (int n = 0; n < 4; ++n) {
        const int col = d0 + 16 * n + lr;
        const size_t idx = ((size_t)b * H + row) * D + col;
        Zn[idx] = fmaf(p0, Z0[idx], accz[m][n][j]);
        Fn[idx] = fmaf(p0, F0[idx], accf[m][n][j]);
      }
    }
}

}  // namespace

extern "C" void kernel_launch(void* const* d_in, const int* in_sizes, int n_in,
                              void* d_out, int out_size, void* d_ws,
                              size_t ws_size, hipStream_t stream) {
  const float* x = (const float*)d_in[0];
  const float* hidden_prev = (const float*)d_in[1];
  const float* Z_state = (const float*)d_in[2];
  const float* F_state = (const float*)d_in[3];
  const float* wz_state = (const float*)d_in[4];
  const float* wf_state = (const float*)d_in[5];
  const float* bz_state = (const float*)d_in[6];
  const float* bf_state = (const float*)d_in[7];
  const float* wm_z = (const float*)d_in[8];
  const float* wm_f = (const float*)d_in[9];
  const float* wv_z = (const float*)d_in[10];
  const float* wv_f = (const float*)d_in[11];
  const float* bias_z = (const float*)d_in[12];
  const float* bias_f = (const float*)d_in[13];

  // Workspace (~60 MB): pzf (33.5M, becomes {zffz,common} in-place) |
  // azf 16.8M | xb 8.4M | weights 1M | P0
  float2* pzf = (float2*)d_ws;                   // [SBH]
  uint32* azf = (uint32*)(pzf + SBH);            // [SBH]
  ushort16* xb = (ushort16*)(azf + SBH);         // [XN]
  ushort16* wmzb = xb + XN;                      // [WN]
  ushort16* wmfb = wmzb + WN;                    // [WN]
  float* P0 = (float*)(wmfb + WN);               // [BH]

  float* out = (float*)d_out;
  float* out_cells = out;                        // S*B*H
  float* out_newcell = out + SBH;                // B*H
  float* out_Zn = out_newcell + BH;              // B*H*D
  float* out_Fn = out_Zn + (size_t)BH * D;       // B*H*D
  float* out_wzn = out_Fn + (size_t)BH * D;      // B*H
  float* out_wfn = out_wzn + BH;
  float* out_bzn = out_wfn + BH;
  float* out_bfn = out_bzn + BH;

  convert_kernel<<<(XN + 2 * WN) / 8 / 256, 256, 0, stream>>>(
      x, wm_z, wm_f, xb, wmzb, wmfb);
  proj_gemm<<<dim3(M1 / 128, H / 64), 256, 0, stream>>>(xb, wmzb, wmfb, pzf);
  scan_fwd<<<BH / 64, 64, 0, stream>>>(
      hidden_prev, wz_state, wf_state, bz_state, bf_state, wv_z, wv_f, bias_z,
      bias_f, pzf, out_cells, out_newcell, out_wzn, out_wfn, out_bzn,
      out_bfn);
  suffix_kernel<<<BH / 64, 1024, 0, stream>>>(pzf, azf, P0);
  out_gemm<<<dim3(H / 128, D / 64, B), 256, 0, stream>>>(
      azf, xb, P0, Z_state, F_state, out_Zn, out_Fn);
}